// Round 9
// baseline (170.067 us; speedup 1.0000x reference)
//
#include <hip/hip_runtime.h>

#define NNODES 100000
#define EDGES  262144
#define NTILES 3125          // NNODES / 32
#define GEMM_BLOCKS 256

typedef __attribute__((ext_vector_type(8))) short short8v;
typedef __attribute__((ext_vector_type(8))) unsigned short ushort8v;
typedef __attribute__((ext_vector_type(4))) float f32x4;

__device__ __forceinline__ unsigned short f2bf(float f) {
  unsigned u = __builtin_bit_cast(unsigned, f);
  u += 0x7fffu + ((u >> 16) & 1u);
  return (unsigned short)(u >> 16);
}
__device__ __forceinline__ float bf2f(unsigned short u) {
  return __builtin_bit_cast(float, (unsigned)u << 16);
}
// HW packed f32->bf16 (RNE), two values -> one dword [lo|hi]
__device__ __forceinline__ unsigned cvt_pk(float lo, float hi) {
  unsigned r;
  asm volatile("v_cvt_pk_bf16_f32 %0, %1, %2" : "=v"(r) : "v"(lo), "v"(hi));
  return r;
}

// ---------------------------------------------------------------------------
// Kernel 0: repack W1 (fp32 [256][512]) -> Wc (bf16 [512][256], k-major).
// Row j<256  = src-projection row j  (W1 cols 0:128 then 256:384)
// Row j>=256 = dst-projection row j-256 (W1 cols 128:256 then 384:512)
// (proven rounds 1-2)
// ---------------------------------------------------------------------------
__global__ __launch_bounds__(256) void prep_wc(const float* __restrict__ W1,
                                               unsigned short* __restrict__ Wc) {
  int idx = blockIdx.x * 256 + threadIdx.x;   // 0 .. 512*256-1
  int j = idx >> 8;
  int k = idx & 255;
  int jj = j & 255;
  int kk = (k < 128) ? k : (k + 128);
  if (j >= 256) kk += 128;
  Wc[idx] = f2bf(W1[jj * 512 + kk]);
}

// ---------------------------------------------------------------------------
// GEMM, r8 skeleton; delta: NO persistent B panel.  B fragments are re-loaded
// from L2-resident prepacked Wc (256 KB, shared by all blocks) inside the
// K-loop, '#pragma unroll 1' keeps live pressure ~60 regs < the allocator's
// 64-reg choice -> genuinely NO spill (r3-r8 all spilled bfrag).  Latency of
// per-ks L2 loads hidden by TLP (2 blocks/CU = 32 waves/CU resident).
//
// P[n][j] = sum_k h[n][k]*Wc[j][k] + (j<256 ? b1[j] : 0)
// Swapped-operand MFMA: C row = j, col = node -> packed uint2 stores.
// ---------------------------------------------------------------------------
__global__ __launch_bounds__(1024)
void gemm_proj9(const float* __restrict__ ne,
                const float* __restrict__ mem,
                const unsigned short* __restrict__ Wc,
                const float* __restrict__ b1,
                unsigned short* __restrict__ P) {
  __shared__ __align__(16) unsigned short As[2][32][272];  // 0 bank conflicts (r6-r8)
  const int tid  = threadIdx.x;
  const int bid  = blockIdx.x;
  const int wid  = tid >> 6;          // 0..15
  const int lane = tid & 63;
  const int lr   = lane & 15;
  const int kq   = (lane >> 4) * 8;   // 0,8,16,24
  const int cb   = wid * 32;          // this wave's j base (0..480)

  // ---- bias quad per jt (j = cb + jt*16 + (lane>>4)*4 + r), src half only ----
  float4 b1v[2];
#pragma unroll
  for (int jt = 0; jt < 2; ++jt) {
    if (cb < 256) b1v[jt] = *(const float4*)(b1 + cb + jt * 16 + (lane >> 4) * 4);
    else          b1v[jt] = float4{0.f, 0.f, 0.f, 0.f};
  }

  // per-lane B row pointers (j = cb+lr and cb+16+lr), k-major rows of 256
  const unsigned short* wp0 = Wc + (size_t)(cb + lr) * 256 + kq;
  const unsigned short* wp1 = wp0 + 16 * 256;

  const int nt = (NTILES - bid + GEMM_BLOCKS - 1) / GEMM_BLOCKS;  // 12 or 13

  // ---- stage tile 0 (2048 float4-chunks / 1024 thr -> g[2]) ----
  float4 g[2];
#pragma unroll
  for (int i = 0; i < 2; ++i) {
    int q = tid + i * 1024;           // 0..2047
    int row = q >> 6;
    int k0  = (q & 63) * 4;
    int node = bid * 32 + row;
    g[i] = *(const float4*)((k0 < 128) ? ne + (size_t)node * 128 + k0
                                       : mem + (size_t)node * 128 + (k0 - 128));
  }
#pragma unroll
  for (int i = 0; i < 2; ++i) {
    int q = tid + i * 1024;
    int row = q >> 6;
    int k0  = (q & 63) * 4;
    uint2 pk { cvt_pk(g[i].x, g[i].y), cvt_pk(g[i].z, g[i].w) };
    *(uint2*)&As[0][row][k0] = pk;
  }
  __syncthreads();

  for (int it = 0; it < nt; ++it) {
    const int tile = bid + it * GEMM_BLOCKS;
    const int buf  = it & 1;
    const bool more = (it + 1 < nt);

    // issue next tile's global loads EARLY (hide HBM latency under MFMA)
    if (more) {
      const int ntile = bid + (it + 1) * GEMM_BLOCKS;
#pragma unroll
      for (int i = 0; i < 2; ++i) {
        int q = tid + i * 1024;
        int row = q >> 6;
        int k0  = (q & 63) * 4;
        int node = ntile * 32 + row;
        g[i] = *(const float4*)((k0 < 128) ? ne + (size_t)node * 128 + k0
                                           : mem + (size_t)node * 128 + (k0 - 128));
      }
    }

    // ---- MFMA over K=256; B streamed from L2 each ks (loop kept rolled) ----
    f32x4 acc[2][2] = {};
#pragma unroll 1
    for (int ks = 0; ks < 8; ++ks) {
      const int kk = ks * 32 + kq;
      ushort8v b0 = *(const ushort8v*)(wp0 + ks * 32);
      ushort8v b1f = *(const ushort8v*)(wp1 + ks * 32);
      ushort8v a0 = *(const ushort8v*)&As[buf][lr][kk];        // nodes 0..15
      ushort8v a1 = *(const ushort8v*)&As[buf][lr + 16][kk];   // nodes 16..31
      acc[0][0] = __builtin_amdgcn_mfma_f32_16x16x32_bf16((short8v)b0,  (short8v)a0, acc[0][0], 0, 0, 0);
      acc[0][1] = __builtin_amdgcn_mfma_f32_16x16x32_bf16((short8v)b0,  (short8v)a1, acc[0][1], 0, 0, 0);
      acc[1][0] = __builtin_amdgcn_mfma_f32_16x16x32_bf16((short8v)b1f, (short8v)a0, acc[1][0], 0, 0, 0);
      acc[1][1] = __builtin_amdgcn_mfma_f32_16x16x32_bf16((short8v)b1f, (short8v)a1, acc[1][1], 0, 0, 0);
    }

    // ---- store: C row = j (4 consecutive per lane -> 8B packed store) ----
#pragma unroll
    for (int jt = 0; jt < 2; ++jt)
#pragma unroll
      for (int h = 0; h < 2; ++h) {
        int node = tile * 32 + h * 16 + lr;
        f32x4 v = acc[jt][h];
        uint2 pk { cvt_pk(v[0] + b1v[jt].x, v[1] + b1v[jt].y),
                   cvt_pk(v[2] + b1v[jt].z, v[3] + b1v[jt].w) };
        *(uint2*)(P + (size_t)node * 512 + cb + jt * 16 + (lane >> 4) * 4) = pk;
      }

    // write next tile into the OTHER buffer; one barrier per tile
    if (more) {
#pragma unroll
      for (int i = 0; i < 2; ++i) {
        int q = tid + i * 1024;
        int row = q >> 6;
        int k0  = (q & 63) * 4;
        uint2 pk { cvt_pk(g[i].x, g[i].y), cvt_pk(g[i].z, g[i].w) };
        *(uint2*)&As[buf ^ 1][row][k0] = pk;
      }
    }
    __syncthreads();
  }
}

// ---------------------------------------------------------------------------
// Edge score, 2 edges per wave (half-wave each, 16B/lane) — proven r2/r3/r6-r8.
// out[e] = relu(P[src][0:256] + P[dst][256:512]) . W2 + b2
// ---------------------------------------------------------------------------
__global__ __launch_bounds__(256) void edge_score2(const int* __restrict__ src,
                                                   const int* __restrict__ dst,
                                                   const unsigned short* __restrict__ P,
                                                   const float* __restrict__ W2,
                                                   const float* __restrict__ b2,
                                                   float* __restrict__ out) {
  const int wid  = threadIdx.x >> 6;
  const int lane = threadIdx.x & 63;
  const int half = lane >> 5;
  const int l5   = lane & 31;
  const int e    = blockIdx.x * 8 + wid * 2 + half;

  float4 w0 = *(const float4*)(W2 + l5 * 8);
  float4 w1 = *(const float4*)(W2 + l5 * 8 + 4);
  const float b2c = b2[0];

  const int s = src[e];
  const int d = dst[e];

  ushort8v a = *(const ushort8v*)(P + (size_t)s * 512 + l5 * 8);
  ushort8v b = *(const ushort8v*)(P + (size_t)d * 512 + 256 + l5 * 8);

  float h0 = bf2f(a[0]) + bf2f(b[0]); h0 = h0 > 0.f ? h0 : 0.f;
  float h1 = bf2f(a[1]) + bf2f(b[1]); h1 = h1 > 0.f ? h1 : 0.f;
  float h2 = bf2f(a[2]) + bf2f(b[2]); h2 = h2 > 0.f ? h2 : 0.f;
  float h3 = bf2f(a[3]) + bf2f(b[3]); h3 = h3 > 0.f ? h3 : 0.f;
  float h4 = bf2f(a[4]) + bf2f(b[4]); h4 = h4 > 0.f ? h4 : 0.f;
  float h5 = bf2f(a[5]) + bf2f(b[5]); h5 = h5 > 0.f ? h5 : 0.f;
  float h6 = bf2f(a[6]) + bf2f(b[6]); h6 = h6 > 0.f ? h6 : 0.f;
  float h7 = bf2f(a[7]) + bf2f(b[7]); h7 = h7 > 0.f ? h7 : 0.f;

  float partial = h0 * w0.x + h1 * w0.y + h2 * w0.z + h3 * w0.w
                + h4 * w1.x + h5 * w1.y + h6 * w1.z + h7 * w1.w;

#pragma unroll
  for (int off = 16; off; off >>= 1) partial += __shfl_xor(partial, off, 64);

  if (l5 == 0) out[e] = partial + b2c;
}

// ---------------------------------------------------------------------------
// Fallback (only if ws_size too small): direct per-edge MLP, 8 edges / block.
// ---------------------------------------------------------------------------
__global__ __launch_bounds__(256) void fallback_edge(const int* __restrict__ src,
                                                     const int* __restrict__ dst,
                                                     const float* __restrict__ ne,
                                                     const float* __restrict__ mem,
                                                     const float* __restrict__ W1,
                                                     const float* __restrict__ b1,
                                                     const float* __restrict__ W2,
                                                     const float* __restrict__ b2,
                                                     float* __restrict__ out) {
  __shared__ float hs[8][512];
  __shared__ float red[8][4];
  const int tid = threadIdx.x;
  const int e0  = blockIdx.x * 8;

  for (int idx = tid; idx < 8 * 512; idx += 256) {
    int e8 = idx >> 9, k = idx & 511;
    int e = e0 + e8;
    int s = src[e], d = dst[e];
    float v;
    if (k < 128)      v = ne[(size_t)s * 128 + k];
    else if (k < 256) v = ne[(size_t)d * 128 + k - 128];
    else if (k < 384) v = mem[(size_t)s * 128 + k - 256];
    else              v = mem[(size_t)d * 128 + k - 384];
    hs[e8][k] = v;
  }
  __syncthreads();

  const int j = tid;
  float acc[8] = {0, 0, 0, 0, 0, 0, 0, 0};
  const float* w1r = W1 + (size_t)j * 512;
  for (int k = 0; k < 512; k += 4) {
    float4 w = *(const float4*)(w1r + k);
#pragma unroll
    for (int e8 = 0; e8 < 8; ++e8)
      acc[e8] += hs[e8][k] * w.x + hs[e8][k + 1] * w.y + hs[e8][k + 2] * w.z + hs[e8][k + 3] * w.w;
  }
  const float bj = b1[j], wj = W2[j];
#pragma unroll
  for (int e8 = 0; e8 < 8; ++e8) {
    float h = acc[e8] + bj;
    h = h > 0.f ? h : 0.f;
    acc[e8] = h * wj;
  }
  const int lane = tid & 63, wid = tid >> 6;
#pragma unroll
  for (int e8 = 0; e8 < 8; ++e8) {
    float p = acc[e8];
#pragma unroll
    for (int off = 32; off; off >>= 1) p += __shfl_xor(p, off, 64);
    if (lane == 0) red[e8][wid] = p;
  }
  __syncthreads();
  if (tid < 8) out[e0 + tid] = red[tid][0] + red[tid][1] + red[tid][2] + red[tid][3] + b2[0];
}

// ---------------------------------------------------------------------------
extern "C" void kernel_launch(void* const* d_in, const int* in_sizes, int n_in,
                              void* d_out, int out_size, void* d_ws, size_t ws_size,
                              hipStream_t stream) {
  const int*   src      = (const int*)d_in[0];
  const int*   dst      = (const int*)d_in[1];
  const float* node_emb = (const float*)d_in[4];
  const float* memv     = (const float*)d_in[5];
  const float* W1       = (const float*)d_in[10];
  const float* b1       = (const float*)d_in[11];
  const float* W2       = (const float*)d_in[12];
  const float* b2       = (const float*)d_in[13];
  float*       out      = (float*)d_out;

  const size_t P_BYTES  = (size_t)NNODES * 512 * 2;   // 102,400,000
  const size_t WC_BYTES = (size_t)512 * 256 * 2;      //     262,144

  if (ws_size >= P_BYTES + WC_BYTES) {
    unsigned short* P  = (unsigned short*)d_ws;
    unsigned short* Wc = (unsigned short*)((char*)d_ws + P_BYTES);
    prep_wc<<<512, 256, 0, stream>>>(W1, Wc);
    gemm_proj9<<<GEMM_BLOCKS, 1024, 0, stream>>>(node_emb, memv, Wc, b1, P);
    edge_score2<<<EDGES / 8, 256, 0, stream>>>(src, dst, P, W2, b2, out);
  } else {
    fallback_edge<<<EDGES / 8, 256, 0, stream>>>(src, dst, node_emb, memv, W1, b1, W2, b2, out);
  }
}

// Round 10
// 94.981 us; speedup vs baseline: 1.7905x; 1.7905x over previous
//
#include <hip/hip_runtime.h>

#define NNODES 100000
#define EDGES  262144
#define NTILES 3125          // NNODES / 32
#define GEMM_BLOCKS 256

typedef __attribute__((ext_vector_type(8))) short short8v;
typedef __attribute__((ext_vector_type(8))) unsigned short ushort8v;
typedef __attribute__((ext_vector_type(4))) float f32x4;

__device__ __forceinline__ unsigned short f2bf(float f) {
  unsigned u = __builtin_bit_cast(unsigned, f);
  u += 0x7fffu + ((u >> 16) & 1u);
  return (unsigned short)(u >> 16);
}
__device__ __forceinline__ float bf2f(unsigned short u) {
  return __builtin_bit_cast(float, (unsigned)u << 16);
}
// HW packed f32->bf16 (RNE), two values -> one dword [lo|hi]
__device__ __forceinline__ unsigned cvt_pk(float lo, float hi) {
  unsigned r;
  asm volatile("v_cvt_pk_bf16_f32 %0, %1, %2" : "=v"(r) : "v"(lo), "v"(hi));
  return r;
}

// ---------------------------------------------------------------------------
// Kernel 0: repack W1 (fp32 [256][512]) -> Wc (bf16 [512][256], k-major).
// Row j<256  = src-projection row j  (W1 cols 0:128 then 256:384)
// Row j>=256 = dst-projection row j-256 (W1 cols 128:256 then 384:512)
// (proven r1/r2/r9)
// ---------------------------------------------------------------------------
__global__ __launch_bounds__(256) void prep_wc(const float* __restrict__ W1,
                                               unsigned short* __restrict__ Wc) {
  int idx = blockIdx.x * 256 + threadIdx.x;   // 0 .. 512*256-1
  int j = idx >> 8;
  int k = idx & 255;
  int jj = j & 255;
  int kk = (k < 128) ? k : (k + 128);
  if (j >= 256) kk += 128;
  Wc[idx] = f2bf(W1[jj * 512 + kk]);
}

// ---------------------------------------------------------------------------
// GEMM = r2's proven remat-friendly structure + r3's proven packed epilogue.
// 512 thr = 8 waves; wave owns 64 j.  bfrag[8][4] is *declared* persistent but
// sourced from bf16 Wc by plain 16B loads -> at the 128-VGPR cap the compiler
// REMATERIALIZES them from L2 (r2: ~65us) instead of scratch-spilling
// (r3-r8: W1-sourced frags embed f2bf arithmetic -> true spill, +78 MB WRITE).
// Full unroll keeps ILP (r9's rolled loop at 32 VGPR serialized: 147us).
//
// P[n][j] = sum_k h[n][k]*Wc[j][k] + (j<256 ? b1[j] : 0)
// Swapped-operand MFMA: C row = j, col = node -> 4 consecutive j per lane ->
// packed uint2 stores (proven r3).
// ---------------------------------------------------------------------------
__global__ __launch_bounds__(512)
void gemm_proj10(const float* __restrict__ ne,
                 const float* __restrict__ mem,
                 const unsigned short* __restrict__ Wc,
                 const float* __restrict__ b1,
                 unsigned short* __restrict__ P) {
  __shared__ __align__(16) unsigned short As[2][32][272];  // stride 272: 0 conflicts (r6-r8)
  const int tid  = threadIdx.x;
  const int bid  = blockIdx.x;
  const int wid  = tid >> 6;          // 0..7
  const int lane = tid & 63;
  const int lr   = lane & 15;
  const int kq   = (lane >> 4) * 8;   // 0,8,16,24
  const int cb   = wid * 64;          // this wave's j base

  // ---- B panel (MFMA A-operand): plain 16B loads from Wc -> remat-able ----
  ushort8v bfrag[8][4];
#pragma unroll
  for (int ks = 0; ks < 8; ++ks)
#pragma unroll
    for (int jt = 0; jt < 4; ++jt)
      bfrag[ks][jt] = *(const ushort8v*)(Wc + (size_t)(cb + jt * 16 + lr) * 256 + ks * 32 + kq);

  const int nt = (NTILES - bid + GEMM_BLOCKS - 1) / GEMM_BLOCKS;  // 12 or 13

  // ---- stage tile 0 (2048 float4-chunks / 512 thr -> g[4]) ----
  float4 g[4];
#pragma unroll
  for (int i = 0; i < 4; ++i) {
    int q = tid + i * 512;            // 0..2047
    int row = q >> 6;
    int k0  = (q & 63) * 4;
    int node = bid * 32 + row;
    g[i] = *(const float4*)((k0 < 128) ? ne + (size_t)node * 128 + k0
                                       : mem + (size_t)node * 128 + (k0 - 128));
  }
#pragma unroll
  for (int i = 0; i < 4; ++i) {
    int q = tid + i * 512;
    int row = q >> 6;
    int k0  = (q & 63) * 4;
    uint2 pk { cvt_pk(g[i].x, g[i].y), cvt_pk(g[i].z, g[i].w) };
    *(uint2*)&As[0][row][k0] = pk;
  }
  __syncthreads();

  for (int it = 0; it < nt; ++it) {
    const int tile = bid + it * GEMM_BLOCKS;
    const int buf  = it & 1;
    const bool more = (it + 1 < nt);

    // issue next tile's global loads EARLY (hide HBM latency under MFMA)
    if (more) {
      const int ntile = bid + (it + 1) * GEMM_BLOCKS;
#pragma unroll
      for (int i = 0; i < 4; ++i) {
        int q = tid + i * 512;
        int row = q >> 6;
        int k0  = (q & 63) * 4;
        int node = ntile * 32 + row;
        g[i] = *(const float4*)((k0 < 128) ? ne + (size_t)node * 128 + k0
                                           : mem + (size_t)node * 128 + (k0 - 128));
      }
    }

    // ---- MFMA over K=256 (swapped: A=W-frag, B=node-frag), fully unrolled ----
    f32x4 acc[4][2] = {};
#pragma unroll
    for (int ks = 0; ks < 8; ++ks) {
      const int kk = ks * 32 + kq;
      ushort8v a0 = *(const ushort8v*)&As[buf][lr][kk];        // nodes 0..15
      ushort8v a1 = *(const ushort8v*)&As[buf][lr + 16][kk];   // nodes 16..31
#pragma unroll
      for (int jt = 0; jt < 4; ++jt) {
        acc[jt][0] = __builtin_amdgcn_mfma_f32_16x16x32_bf16((short8v)bfrag[ks][jt], (short8v)a0, acc[jt][0], 0, 0, 0);
        acc[jt][1] = __builtin_amdgcn_mfma_f32_16x16x32_bf16((short8v)bfrag[ks][jt], (short8v)a1, acc[jt][1], 0, 0, 0);
      }
    }

    // ---- store: C row = j (4 consecutive per lane -> one 8B packed store) ----
#pragma unroll
    for (int jt = 0; jt < 4; ++jt) {
      const int jq = cb + jt * 16 + (lane >> 4) * 4;     // lane's 4-j base
      float4 bv = (cb < 256) ? *(const float4*)(b1 + jq) : float4{0.f, 0.f, 0.f, 0.f};
#pragma unroll
      for (int h = 0; h < 2; ++h) {
        int node = tile * 32 + h * 16 + lr;
        f32x4 v = acc[jt][h];
        uint2 pk { cvt_pk(v[0] + bv.x, v[1] + bv.y),
                   cvt_pk(v[2] + bv.z, v[3] + bv.w) };
        *(uint2*)(P + (size_t)node * 512 + jq) = pk;
      }
    }

    // write next tile into the OTHER buffer; one barrier per tile
    if (more) {
#pragma unroll
      for (int i = 0; i < 4; ++i) {
        int q = tid + i * 512;
        int row = q >> 6;
        int k0  = (q & 63) * 4;
        uint2 pk { cvt_pk(g[i].x, g[i].y), cvt_pk(g[i].z, g[i].w) };
        *(uint2*)&As[buf ^ 1][row][k0] = pk;
      }
    }
    __syncthreads();
  }
}

// ---------------------------------------------------------------------------
// Edge score, 2 edges per wave (half-wave each, 16B/lane) — proven r2/r3/r6-r9.
// out[e] = relu(P[src][0:256] + P[dst][256:512]) . W2 + b2
// ---------------------------------------------------------------------------
__global__ __launch_bounds__(256) void edge_score2(const int* __restrict__ src,
                                                   const int* __restrict__ dst,
                                                   const unsigned short* __restrict__ P,
                                                   const float* __restrict__ W2,
                                                   const float* __restrict__ b2,
                                                   float* __restrict__ out) {
  const int wid  = threadIdx.x >> 6;
  const int lane = threadIdx.x & 63;
  const int half = lane >> 5;
  const int l5   = lane & 31;
  const int e    = blockIdx.x * 8 + wid * 2 + half;

  float4 w0 = *(const float4*)(W2 + l5 * 8);
  float4 w1 = *(const float4*)(W2 + l5 * 8 + 4);
  const float b2c = b2[0];

  const int s = src[e];
  const int d = dst[e];

  ushort8v a = *(const ushort8v*)(P + (size_t)s * 512 + l5 * 8);
  ushort8v b = *(const ushort8v*)(P + (size_t)d * 512 + 256 + l5 * 8);

  float h0 = bf2f(a[0]) + bf2f(b[0]); h0 = h0 > 0.f ? h0 : 0.f;
  float h1 = bf2f(a[1]) + bf2f(b[1]); h1 = h1 > 0.f ? h1 : 0.f;
  float h2 = bf2f(a[2]) + bf2f(b[2]); h2 = h2 > 0.f ? h2 : 0.f;
  float h3 = bf2f(a[3]) + bf2f(b[3]); h3 = h3 > 0.f ? h3 : 0.f;
  float h4 = bf2f(a[4]) + bf2f(b[4]); h4 = h4 > 0.f ? h4 : 0.f;
  float h5 = bf2f(a[5]) + bf2f(b[5]); h5 = h5 > 0.f ? h5 : 0.f;
  float h6 = bf2f(a[6]) + bf2f(b[6]); h6 = h6 > 0.f ? h6 : 0.f;
  float h7 = bf2f(a[7]) + bf2f(b[7]); h7 = h7 > 0.f ? h7 : 0.f;

  float partial = h0 * w0.x + h1 * w0.y + h2 * w0.z + h3 * w0.w
                + h4 * w1.x + h5 * w1.y + h6 * w1.z + h7 * w1.w;

#pragma unroll
  for (int off = 16; off; off >>= 1) partial += __shfl_xor(partial, off, 64);

  if (l5 == 0) out[e] = partial + b2c;
}

// ---------------------------------------------------------------------------
// Fallback (only if ws_size too small): direct per-edge MLP, 8 edges / block.
// ---------------------------------------------------------------------------
__global__ __launch_bounds__(256) void fallback_edge(const int* __restrict__ src,
                                                     const int* __restrict__ dst,
                                                     const float* __restrict__ ne,
                                                     const float* __restrict__ mem,
                                                     const float* __restrict__ W1,
                                                     const float* __restrict__ b1,
                                                     const float* __restrict__ W2,
                                                     const float* __restrict__ b2,
                                                     float* __restrict__ out) {
  __shared__ float hs[8][512];
  __shared__ float red[8][4];
  const int tid = threadIdx.x;
  const int e0  = blockIdx.x * 8;

  for (int idx = tid; idx < 8 * 512; idx += 256) {
    int e8 = idx >> 9, k = idx & 511;
    int e = e0 + e8;
    int s = src[e], d = dst[e];
    float v;
    if (k < 128)      v = ne[(size_t)s * 128 + k];
    else if (k < 256) v = ne[(size_t)d * 128 + k - 128];
    else if (k < 384) v = mem[(size_t)s * 128 + k - 256];
    else              v = mem[(size_t)d * 128 + k - 384];
    hs[e8][k] = v;
  }
  __syncthreads();

  const int j = tid;
  float acc[8] = {0, 0, 0, 0, 0, 0, 0, 0};
  const float* w1r = W1 + (size_t)j * 512;
  for (int k = 0; k < 512; k += 4) {
    float4 w = *(const float4*)(w1r + k);
#pragma unroll
    for (int e8 = 0; e8 < 8; ++e8)
      acc[e8] += hs[e8][k] * w.x + hs[e8][k + 1] * w.y + hs[e8][k + 2] * w.z + hs[e8][k + 3] * w.w;
  }
  const float bj = b1[j], wj = W2[j];
#pragma unroll
  for (int e8 = 0; e8 < 8; ++e8) {
    float h = acc[e8] + bj;
    h = h > 0.f ? h : 0.f;
    acc[e8] = h * wj;
  }
  const int lane = tid & 63, wid = tid >> 6;
#pragma unroll
  for (int e8 = 0; e8 < 8; ++e8) {
    float p = acc[e8];
#pragma unroll
    for (int off = 32; off; off >>= 1) p += __shfl_xor(p, off, 64);
    if (lane == 0) red[e8][wid] = p;
  }
  __syncthreads();
  if (tid < 8) out[e0 + tid] = red[tid][0] + red[tid][1] + red[tid][2] + red[tid][3] + b2[0];
}

// ---------------------------------------------------------------------------
extern "C" void kernel_launch(void* const* d_in, const int* in_sizes, int n_in,
                              void* d_out, int out_size, void* d_ws, size_t ws_size,
                              hipStream_t stream) {
  const int*   src      = (const int*)d_in[0];
  const int*   dst      = (const int*)d_in[1];
  const float* node_emb = (const float*)d_in[4];
  const float* memv     = (const float*)d_in[5];
  const float* W1       = (const float*)d_in[10];
  const float* b1       = (const float*)d_in[11];
  const float* W2       = (const float*)d_in[12];
  const float* b2       = (const float*)d_in[13];
  float*       out      = (float*)d_out;

  const size_t P_BYTES  = (size_t)NNODES * 512 * 2;   // 102,400,000
  const size_t WC_BYTES = (size_t)512 * 256 * 2;      //     262,144

  if (ws_size >= P_BYTES + WC_BYTES) {
    unsigned short* P  = (unsigned short*)d_ws;
    unsigned short* Wc = (unsigned short*)((char*)d_ws + P_BYTES);
    prep_wc<<<512, 256, 0, stream>>>(W1, Wc);
    gemm_proj10<<<GEMM_BLOCKS, 512, 0, stream>>>(node_emb, memv, Wc, b1, P);
    edge_score2<<<EDGES / 8, 256, 0, stream>>>(src, dst, P, W2, b2, out);
  } else {
    fallback_edge<<<EDGES / 8, 256, 0, stream>>>(src, dst, node_emb, memv, W1, b1, W2, b2, out);
  }
}